// Round 1
// baseline (435.894 us; speedup 1.0000x reference)
//
#include <hip/hip_runtime.h>

#define NB 8
#define NA 32768
#define NC 80
#define NM 32
#define NK 50
constexpr float VAR0 = 0.1f, VAR1 = 0.2f;
constexpr float T1f  = 0.5f;
constexpr float SL1B = 0.11f;
constexpr float SL1W = 0.75f;
constexpr float FEPS = 1e-12f;

__device__ __forceinline__ float iou_corner(float tx0, float ty0, float tx1, float ty1, float ta,
                                            float bx0, float by0, float bx1, float by1, float ba) {
  float lx = fmaxf(tx0, bx0), ly = fmaxf(ty0, by0);
  float rx = fminf(tx1, bx1), ry = fminf(ty1, by1);
  float wx = fmaxf(rx - lx, 0.f), wy = fmaxf(ry - ly, 0.f);
  float inter = wx * wy;
  return inter / (ta + ba - inter);
}

// ---- K1: per (b,m) max IoU(target, decoded boxes) -> inv_denom ----
__global__ void __launch_bounds__(256) t2_kernel(const float4* __restrict__ br,
                                                 const float4* __restrict__ anc,
                                                 const float4* __restrict__ tgt,
                                                 float* __restrict__ inv_denom) {
  int bm = blockIdx.x;
  int b = bm >> 5;
  float4 t = tgt[bm];
  float ta = (t.z - t.x) * (t.w - t.y);
  float best = 0.f;
  for (int a = threadIdx.x; a < NA; a += 256) {
    float4 p = anc[a];
    float4 l = br[(size_t)b * NA + a];
    float cx = p.x + l.x * VAR0 * p.z;
    float cy = p.y + l.y * VAR0 * p.w;
    float w = p.z * __expf(l.z * VAR1);
    float h = p.w * __expf(l.w * VAR1);
    float hx = 0.5f * w, hy = 0.5f * h;
    float x0 = cx - hx, y0 = cy - hy, x1 = cx + hx, y1 = cy + hy;
    float da = (x1 - x0) * (y1 - y0);
    best = fmaxf(best, iou_corner(t.x, t.y, t.z, t.w, ta, x0, y0, x1, y1, da));
  }
  for (int off = 32; off; off >>= 1) best = fmaxf(best, __shfl_down(best, off));
  __shared__ float sred[4];
  if ((threadIdx.x & 63) == 0) sred[threadIdx.x >> 6] = best;
  __syncthreads();
  if (threadIdx.x == 0) {
    best = fmaxf(fmaxf(sred[0], sred[1]), fmaxf(sred[2], sred[3]));
    // T1 + 1e-12 rounds to 0.5f in fp32
    float t2v = fmaxf(best, T1f);
    inv_denom[bm] = 1.0f / (t2v - T1f);  // may be +inf; downstream clamps match jnp.clip
  }
}

// ---- K2: per (b,m) exact top-50 + positive bag loss ----
__global__ void __launch_bounds__(256) pos_kernel(const float4* __restrict__ br,
                                                  const float* __restrict__ cls,
                                                  const float4* __restrict__ anc,
                                                  const float4* __restrict__ tgt,
                                                  const int* __restrict__ labels,
                                                  double* __restrict__ acc) {
  __shared__ float smq[NA];       // 128 KiB
  __shared__ float rv[4];
  __shared__ int   ri[4];
  __shared__ int   sel[NK];
  int bm = blockIdx.x;
  int b = bm >> 5;
  float4 t = tgt[bm];
  float ta = (t.z - t.x) * (t.w - t.y);
  for (int a = threadIdx.x; a < NA; a += 256) {
    float4 p = anc[a];
    float hx = 0.5f * p.z, hy = 0.5f * p.w;
    float x0 = p.x - hx, y0 = p.y - hy, x1 = p.x + hx, y1 = p.y + hy;
    float ba = (x1 - x0) * (y1 - y0);
    smq[a] = iou_corner(t.x, t.y, t.z, t.w, ta, x0, y0, x1, y1, ba);
  }
  __syncthreads();

  // 50 iterative argmax extractions. Tie-break: larger value, then smaller index
  // (matches jax.lax.top_k stability).
  for (int k = 0; k < NK; ++k) {
    float bv = -1.f; int bi = NA;
    for (int i = threadIdx.x; i < NA; i += 256) {
      float v = smq[i];
      if (v > bv) { bv = v; bi = i; }   // strict >: keeps smallest index within thread
    }
    for (int off = 32; off; off >>= 1) {
      float ov = __shfl_down(bv, off);
      int   oi = __shfl_down(bi, off);
      if (ov > bv || (ov == bv && oi < bi)) { bv = ov; bi = oi; }
    }
    if ((threadIdx.x & 63) == 0) { rv[threadIdx.x >> 6] = bv; ri[threadIdx.x >> 6] = bi; }
    __syncthreads();
    if (threadIdx.x == 0) {
      float fv = rv[0]; int fi = ri[0];
      for (int w2 = 1; w2 < 4; ++w2) {
        if (rv[w2] > fv || (rv[w2] == fv && ri[w2] < fi)) { fv = rv[w2]; fi = ri[w2]; }
      }
      sel[k] = fi;
      smq[fi] = -2.f;  // below any real IoU and the -1 sentinel
    }
    __syncthreads();
  }

  // bag loss on wave 0 (lanes 0..49 active)
  if (threadIdx.x < 64) {
    int lane = threadIdx.x;
    float lg = 0.f, wr = 0.f;
    if (lane < NK) {
      int a = sel[lane];
      int lb = labels[bm];
      float4 p = anc[a];
      float4 l = br[(size_t)b * NA + a];
      float logit = cls[((size_t)b * NA + a) * NC + lb];
      float mc = 1.f / (1.f + __expf(-logit));
      float gx = ((t.x + t.z) * 0.5f - p.x) / (VAR0 * p.z);
      float gy = ((t.y + t.w) * 0.5f - p.y) / (VAR0 * p.w);
      float gw = __logf((t.z - t.x) / p.z) / VAR1;
      float gh = __logf((t.w - t.y) / p.w) / VAR1;
      float v0 = gx - l.x, v1 = gy - l.y, v2 = gw - l.z, v3 = gh - l.w;
      float rl = 0.f;
      {
        float av;
        av = fabsf(v0); rl += (av < SL1B) ? (0.5f / SL1B) * v0 * v0 : (av - 0.5f * SL1B);
        av = fabsf(v1); rl += (av < SL1B) ? (0.5f / SL1B) * v1 * v1 : (av - 0.5f * SL1B);
        av = fabsf(v2); rl += (av < SL1B) ? (0.5f / SL1B) * v2 * v2 : (av - 0.5f * SL1B);
        av = fabsf(v3); rl += (av < SL1B) ? (0.5f / SL1B) * v3 * v3 : (av - 0.5f * SL1B);
      }
      rl *= SL1W;
      lg = mc * __expf(-rl);
      wr = 1.f / fmaxf(1.f - lg, FEPS);
    }
    float swl = wr * lg, swr = wr;
    for (int off = 32; off; off >>= 1) { swl += __shfl_down(swl, off); swr += __shfl_down(swr, off); }
    if (lane == 0) {
      float bag = swl / swr;
      float pos = -fmaxf(logf(fmaxf(bag, 1e-38f)), -100.f);
      atomicAdd(acc + 1, (double)pos);
    }
  }
}

// ---- K3: negative (focal) loss over all (b,a,c) ----
__global__ void __launch_bounds__(256) neg_kernel(const float4* __restrict__ br,
                                                  const float* __restrict__ cls,
                                                  const float4* __restrict__ anc,
                                                  const float4* __restrict__ tgt,
                                                  const int* __restrict__ labels,
                                                  const float* __restrict__ inv_denom,
                                                  double* __restrict__ acc) {
  __shared__ float s_obp[NM][256];   // [m][thread] — lanes consecutive: conflict-free
  __shared__ float4 s_t[NM];
  __shared__ float s_ta[NM], s_inv[NM];
  __shared__ unsigned s_cmask[NC];
  int b = blockIdx.y;
  int tid = threadIdx.x;
  if (tid < NC) s_cmask[tid] = 0u;
  __syncthreads();
  if (tid < NM) {
    float4 t = tgt[b * NM + tid];
    s_t[tid] = t;
    s_ta[tid] = (t.z - t.x) * (t.w - t.y);
    s_inv[tid] = inv_denom[b * NM + tid];
    atomicOr(&s_cmask[labels[b * NM + tid]], 1u << tid);
  }
  __syncthreads();

  int a = blockIdx.x * 256 + tid;
  float4 p = anc[a];
  float4 l = br[(size_t)b * NA + a];
  float cx = p.x + l.x * VAR0 * p.z;
  float cy = p.y + l.y * VAR0 * p.w;
  float w = p.z * __expf(l.z * VAR1);
  float h = p.w * __expf(l.w * VAR1);
  float dx0 = cx - 0.5f * w, dy0 = cy - 0.5f * h;
  float dx1 = cx + 0.5f * w, dy1 = cy + 0.5f * h;
  float da = (dx1 - dx0) * (dy1 - dy0);

#pragma unroll
  for (int m = 0; m < NM; ++m) {
    float4 t = s_t[m];
    float iou = iou_corner(t.x, t.y, t.z, t.w, s_ta[m], dx0, dy0, dx1, dy1, da);
    float o = (iou - T1f) * s_inv[m];
    s_obp[m][tid] = fminf(fmaxf(o, 0.f), 1.f);
  }
  __syncthreads();

  const float4* row = (const float4*)(cls + ((size_t)b * NA + a) * NC);
  float accum = 0.f;
#pragma unroll 4
  for (int j = 0; j < NC / 4; ++j) {
    float4 v = row[j];
    float vv0 = v.x, vv1 = v.y, vv2 = v.z, vv3 = v.w;
#pragma unroll
    for (int e = 0; e < 4; ++e) {
      float lv = (e == 0) ? vv0 : (e == 1) ? vv1 : (e == 2) ? vv2 : vv3;
      int c = 4 * j + e;
      unsigned mk = s_cmask[c];
      float bp = 0.f;
      while (mk) {                     // block-uniform mask: no divergence
        int mm = __ffs(mk) - 1;
        mk &= mk - 1;
        bp = fmaxf(bp, s_obp[mm][tid]);
      }
      float s = 1.f / (1.f + __expf(-lv));
      float pr = s * (1.f - bp);
      float om = fmaxf(1.f - pr, 1e-38f);
      accum += pr * pr * fminf(-__logf(om), 100.f);
    }
  }

  for (int off = 32; off; off >>= 1) accum += __shfl_down(accum, off);
  __shared__ float swave[4];
  if ((tid & 63) == 0) swave[tid >> 6] = accum;
  __syncthreads();
  if (tid == 0) atomicAdd(acc, (double)(swave[0] + swave[1] + swave[2] + swave[3]));
}

// ---- K4: finalize ----
__global__ void fin_kernel(const double* __restrict__ acc, float* __restrict__ out) {
  // positive_numels = NB*NM = 256; ALPHA = 0.5; negative denom = 256*50 = 12800
  out[0] = (float)(acc[1] / 256.0 * 0.5);
  out[1] = (float)(acc[0] / 12800.0 * 0.5);
}

extern "C" void kernel_launch(void* const* d_in, const int* in_sizes, int n_in,
                              void* d_out, int out_size, void* d_ws, size_t ws_size,
                              hipStream_t stream) {
  const float4* br  = (const float4*)d_in[0];
  const float*  cls = (const float*)d_in[1];
  const float4* anc = (const float4*)d_in[2];
  const float4* tgt = (const float4*)d_in[3];
  const int*    lab = (const int*)d_in[4];
  float* out = (float*)d_out;
  double* acc = (double*)d_ws;                       // [0]=neg, [1]=pos
  float* inv_denom = (float*)((char*)d_ws + 16);     // 256 floats

  hipMemsetAsync(d_ws, 0, 16, stream);
  t2_kernel<<<dim3(NB * NM), 256, 0, stream>>>(br, anc, tgt, inv_denom);
  pos_kernel<<<dim3(NB * NM), 256, 0, stream>>>(br, cls, anc, tgt, lab, acc);
  neg_kernel<<<dim3(NA / 256, NB), 256, 0, stream>>>(br, cls, anc, tgt, lab, inv_denom, acc);
  fin_kernel<<<1, 1, 0, stream>>>(acc, out);
}

// Round 2
// 129.568 us; speedup vs baseline: 3.3642x; 3.3642x over previous
//
#include <hip/hip_runtime.h>

#define NB 8
#define NA 32768
#define NC 80
#define NM 32
#define NK 50
#define CAP 4096
constexpr float VAR0 = 0.1f, VAR1 = 0.2f;
constexpr float T1f  = 0.5f;
constexpr float SL1B = 0.11f;
constexpr float SL1W = 0.75f;
constexpr float FEPS = 1e-12f;

__device__ __forceinline__ float iou_corner(float tx0, float ty0, float tx1, float ty1, float ta,
                                            float bx0, float by0, float bx1, float by1, float ba) {
  float lx = fmaxf(tx0, bx0), ly = fmaxf(ty0, by0);
  float rx = fminf(tx1, bx1), ry = fminf(ty1, by1);
  float wx = fmaxf(rx - lx, 0.f), wy = fmaxf(ry - ly, 0.f);
  float inter = wx * wy;
  return inter / (ta + ba - inter);
}

// __noinline__ so pass1/pass2/pass3 recomputations are bit-identical.
__device__ __noinline__ float anchor_iou(float4 p, float tx0, float ty0, float tx1, float ty1, float ta) {
  float hx = 0.5f * p.z, hy = 0.5f * p.w;
  float x0 = p.x - hx, y0 = p.y - hy, x1 = p.x + hx, y1 = p.y + hy;
  float ba = (x1 - x0) * (y1 - y0);
  return iou_corner(tx0, ty0, tx1, ty1, ta, x0, y0, x1, y1, ba);
}

// ---- K1: per (b,m) max IoU(target, decoded boxes) -> inv_denom ----
__global__ void __launch_bounds__(256) t2_kernel(const float4* __restrict__ br,
                                                 const float4* __restrict__ anc,
                                                 const float4* __restrict__ tgt,
                                                 float* __restrict__ inv_denom) {
  int bm = blockIdx.x;
  int b = bm >> 5;
  float4 t = tgt[bm];
  float ta = (t.z - t.x) * (t.w - t.y);
  float best = 0.f;
  for (int a = threadIdx.x; a < NA; a += 256) {
    float4 p = anc[a];
    float4 l = br[(size_t)b * NA + a];
    float cx = p.x + l.x * VAR0 * p.z;
    float cy = p.y + l.y * VAR0 * p.w;
    float w = p.z * __expf(l.z * VAR1);
    float h = p.w * __expf(l.w * VAR1);
    float hx = 0.5f * w, hy = 0.5f * h;
    float x0 = cx - hx, y0 = cy - hy, x1 = cx + hx, y1 = cy + hy;
    float da = (x1 - x0) * (y1 - y0);
    best = fmaxf(best, iou_corner(t.x, t.y, t.z, t.w, ta, x0, y0, x1, y1, da));
  }
  for (int off = 32; off; off >>= 1) best = fmaxf(best, __shfl_down(best, off));
  __shared__ float sred[4];
  if ((threadIdx.x & 63) == 0) sred[threadIdx.x >> 6] = best;
  __syncthreads();
  if (threadIdx.x == 0) {
    best = fmaxf(fmaxf(sred[0], sred[1]), fmaxf(sred[2], sred[3]));
    float t2v = fmaxf(best, T1f);      // T1 + 1e-12 rounds to 0.5f in fp32
    inv_denom[bm] = 1.0f / (t2v - T1f);
  }
}

// ---- K2: per (b,m) histogram-select exact top-50 + positive bag loss ----
__global__ void __launch_bounds__(512) pos_kernel(const float4* __restrict__ br,
                                                  const float* __restrict__ cls,
                                                  const float4* __restrict__ anc,
                                                  const float4* __restrict__ tgt,
                                                  const int* __restrict__ labels,
                                                  double* __restrict__ acc) {
  __shared__ int hist[512];
  __shared__ unsigned long long cand[CAP];
  __shared__ int sel[NK];
  __shared__ int s_cnt, s_B1, s_filled;
  __shared__ unsigned char s_flag[512];

  int bm = blockIdx.x;
  int b = bm >> 5;
  int tid = threadIdx.x;
  float4 t = tgt[bm];
  float ta = (t.z - t.x) * (t.w - t.y);

  hist[tid] = 0;
  if (tid == 0) { s_cnt = 0; }
  __syncthreads();

  // Pass 1: histogram of IoU float bits (bits 31..21), zeros excluded.
  for (int a = tid; a < NA; a += 512) {
    float iou = anchor_iou(anc[a], t.x, t.y, t.z, t.w, ta);
    if (iou > 0.f) {
      int bin = (int)(__float_as_uint(iou) >> 21);   // <= 508 for iou <= 1.0
      atomicAdd(&hist[bin], 1);
    }
  }
  __syncthreads();

  // Threshold bin: largest B1 s.t. count(bins >= B1) >= NK. Early-exit scan.
  if (tid == 0) {
    int cum = 0, b1 = 0;
    for (int bin = 511; bin >= 0; --bin) {
      cum += hist[bin];
      if (cum >= NK) { b1 = bin; break; }
    }
    s_B1 = b1;
    s_filled = cum;   // if < NK after full scan: fewer than NK positive IoUs
  }
  __syncthreads();
  int B1 = s_B1;
  bool zero_path = (s_filled < NK);

  // Pass 2: collect candidates (bin >= B1) as u64 keys: (valbits<<32) | ~idx.
  // Max key = larger value, tie -> smaller index (jax.lax.top_k order).
  for (int a = tid; a < NA; a += 512) {
    float iou = anchor_iou(anc[a], t.x, t.y, t.z, t.w, ta);
    if (iou > 0.f) {
      unsigned vb = __float_as_uint(iou);
      if ((int)(vb >> 21) >= B1) {
        int slot = atomicAdd(&s_cnt, 1);
        if (slot < CAP)
          cand[slot] = ((unsigned long long)vb << 32) | (unsigned)(~a);
      }
    }
  }
  __syncthreads();
  int n = min(s_cnt, CAP);

  // Rank pass: rank = #keys strictly greater (keys unique). rank<NK -> selected.
  for (int c = tid; c < n; c += 512) {
    unsigned long long key = cand[c];
    int rank = 0;
    for (int j = 0; j < n; ++j) rank += (cand[j] > key);
    if (rank < NK) sel[rank] = (int)(~(unsigned)(key & 0xFFFFFFFFull));
  }
  __syncthreads();

  // Degenerate fill: fewer than NK positives -> smallest-index zero-IoU anchors.
  if (zero_path) {
    if (tid == 0) s_filled = n;
    __syncthreads();
    for (int base = 0; base < NA; base += 512) {
      int a = base + tid;
      float iou = anchor_iou(anc[a], t.x, t.y, t.z, t.w, ta);
      s_flag[tid] = (iou == 0.f);
      __syncthreads();
      if (tid == 0) {
        for (int i = 0; i < 512 && s_filled < NK; ++i)
          if (s_flag[i]) { sel[s_filled++] = base + i; }
      }
      __syncthreads();
      if (s_filled >= NK) break;
    }
  }

  // Bag loss on wave 0 (lanes 0..49 active).
  if (tid < 64) {
    int lane = tid;
    float lg = 0.f, wr = 0.f;
    if (lane < NK) {
      int a = sel[lane];
      int lb = labels[bm];
      float4 p = anc[a];
      float4 l = br[(size_t)b * NA + a];
      float logit = cls[((size_t)b * NA + a) * NC + lb];
      float mc = 1.f / (1.f + __expf(-logit));
      float gx = ((t.x + t.z) * 0.5f - p.x) / (VAR0 * p.z);
      float gy = ((t.y + t.w) * 0.5f - p.y) / (VAR0 * p.w);
      float gw = __logf((t.z - t.x) / p.z) / VAR1;
      float gh = __logf((t.w - t.y) / p.w) / VAR1;
      float v0 = gx - l.x, v1 = gy - l.y, v2 = gw - l.z, v3 = gh - l.w;
      float rl = 0.f;
      {
        float av;
        av = fabsf(v0); rl += (av < SL1B) ? (0.5f / SL1B) * v0 * v0 : (av - 0.5f * SL1B);
        av = fabsf(v1); rl += (av < SL1B) ? (0.5f / SL1B) * v1 * v1 : (av - 0.5f * SL1B);
        av = fabsf(v2); rl += (av < SL1B) ? (0.5f / SL1B) * v2 * v2 : (av - 0.5f * SL1B);
        av = fabsf(v3); rl += (av < SL1B) ? (0.5f / SL1B) * v3 * v3 : (av - 0.5f * SL1B);
      }
      rl *= SL1W;
      lg = mc * __expf(-rl);
      wr = 1.f / fmaxf(1.f - lg, FEPS);
    }
    float swl = wr * lg, swr = wr;
    for (int off = 32; off; off >>= 1) { swl += __shfl_down(swl, off); swr += __shfl_down(swr, off); }
    if (lane == 0) {
      float bag = swl / swr;
      float pos = -fmaxf(logf(fmaxf(bag, 1e-38f)), -100.f);
      atomicAdd(acc + 1, (double)pos);
    }
  }
}

// ---- K3: negative (focal) loss over all (b,a,c) ----
__global__ void __launch_bounds__(256) neg_kernel(const float4* __restrict__ br,
                                                  const float* __restrict__ cls,
                                                  const float4* __restrict__ anc,
                                                  const float4* __restrict__ tgt,
                                                  const int* __restrict__ labels,
                                                  const float* __restrict__ inv_denom,
                                                  double* __restrict__ acc) {
  __shared__ float s_obp[NM][256];   // [m][thread] — lanes consecutive: conflict-free
  __shared__ float4 s_t[NM];
  __shared__ float s_ta[NM], s_inv[NM];
  __shared__ unsigned s_cmask[NC];
  int b = blockIdx.y;
  int tid = threadIdx.x;
  if (tid < NC) s_cmask[tid] = 0u;
  __syncthreads();
  if (tid < NM) {
    float4 t = tgt[b * NM + tid];
    s_t[tid] = t;
    s_ta[tid] = (t.z - t.x) * (t.w - t.y);
    s_inv[tid] = inv_denom[b * NM + tid];
    atomicOr(&s_cmask[labels[b * NM + tid]], 1u << tid);
  }
  __syncthreads();

  int a = blockIdx.x * 256 + tid;
  float4 p = anc[a];
  float4 l = br[(size_t)b * NA + a];
  float cx = p.x + l.x * VAR0 * p.z;
  float cy = p.y + l.y * VAR0 * p.w;
  float w = p.z * __expf(l.z * VAR1);
  float h = p.w * __expf(l.w * VAR1);
  float dx0 = cx - 0.5f * w, dy0 = cy - 0.5f * h;
  float dx1 = cx + 0.5f * w, dy1 = cy + 0.5f * h;
  float da = (dx1 - dx0) * (dy1 - dy0);

#pragma unroll
  for (int m = 0; m < NM; ++m) {
    float4 t = s_t[m];
    float iou = iou_corner(t.x, t.y, t.z, t.w, s_ta[m], dx0, dy0, dx1, dy1, da);
    float o = (iou - T1f) * s_inv[m];
    s_obp[m][tid] = fminf(fmaxf(o, 0.f), 1.f);
  }
  __syncthreads();

  const float4* row = (const float4*)(cls + ((size_t)b * NA + a) * NC);
  float accum = 0.f;
#pragma unroll 4
  for (int j = 0; j < NC / 4; ++j) {
    float4 v = row[j];
    float vv0 = v.x, vv1 = v.y, vv2 = v.z, vv3 = v.w;
#pragma unroll
    for (int e = 0; e < 4; ++e) {
      float lv = (e == 0) ? vv0 : (e == 1) ? vv1 : (e == 2) ? vv2 : vv3;
      int c = 4 * j + e;
      unsigned mk = s_cmask[c];
      float bp = 0.f;
      while (mk) {                     // block-uniform mask: no divergence
        int mm = __ffs(mk) - 1;
        mk &= mk - 1;
        bp = fmaxf(bp, s_obp[mm][tid]);
      }
      float s = 1.f / (1.f + __expf(-lv));
      float pr = s * (1.f - bp);
      float om = fmaxf(1.f - pr, 1e-38f);
      accum += pr * pr * fminf(-__logf(om), 100.f);
    }
  }

  for (int off = 32; off; off >>= 1) accum += __shfl_down(accum, off);
  __shared__ float swave[4];
  if ((tid & 63) == 0) swave[tid >> 6] = accum;
  __syncthreads();
  if (tid == 0) atomicAdd(acc, (double)(swave[0] + swave[1] + swave[2] + swave[3]));
}

// ---- K4: finalize ----
__global__ void fin_kernel(const double* __restrict__ acc, float* __restrict__ out) {
  out[0] = (float)(acc[1] / 256.0 * 0.5);
  out[1] = (float)(acc[0] / 12800.0 * 0.5);
}

extern "C" void kernel_launch(void* const* d_in, const int* in_sizes, int n_in,
                              void* d_out, int out_size, void* d_ws, size_t ws_size,
                              hipStream_t stream) {
  const float4* br  = (const float4*)d_in[0];
  const float*  cls = (const float*)d_in[1];
  const float4* anc = (const float4*)d_in[2];
  const float4* tgt = (const float4*)d_in[3];
  const int*    lab = (const int*)d_in[4];
  float* out = (float*)d_out;
  double* acc = (double*)d_ws;                       // [0]=neg, [1]=pos
  float* inv_denom = (float*)((char*)d_ws + 16);     // 256 floats

  hipMemsetAsync(d_ws, 0, 16, stream);
  t2_kernel<<<dim3(NB * NM), 256, 0, stream>>>(br, anc, tgt, inv_denom);
  pos_kernel<<<dim3(NB * NM), 512, 0, stream>>>(br, cls, anc, tgt, lab, acc);
  neg_kernel<<<dim3(NA / 256, NB), 256, 0, stream>>>(br, cls, anc, tgt, lab, inv_denom, acc);
  fin_kernel<<<1, 1, 0, stream>>>(acc, out);
}

// Round 3
// 102.009 us; speedup vs baseline: 4.2731x; 1.2702x over previous
//
#include <hip/hip_runtime.h>

#define NB 8
#define NA 32768
#define NC 80
#define NM 32
#define NK 50
#define CAP 4096
constexpr float VAR0 = 0.1f, VAR1 = 0.2f;
constexpr float T1f  = 0.5f;
constexpr float SL1B = 0.11f;
constexpr float SL1W = 0.75f;
constexpr float FEPS = 1e-12f;

__device__ __forceinline__ float iou_corner(float tx0, float ty0, float tx1, float ty1, float ta,
                                            float bx0, float by0, float bx1, float by1, float ba) {
  float lx = fmaxf(tx0, bx0), ly = fmaxf(ty0, by0);
  float rx = fminf(tx1, bx1), ry = fminf(ty1, by1);
  float wx = fmaxf(rx - lx, 0.f), wy = fmaxf(ry - ly, 0.f);
  float inter = wx * wy;
  return inter / (ta + ba - inter);
}

// __noinline__ so pos_kernel's pass1/pass2/pass3 recomputations are bit-identical.
__device__ __noinline__ float anchor_iou(float4 p, float tx0, float ty0, float tx1, float ty1, float ta) {
  float hx = 0.5f * p.z, hy = 0.5f * p.w;
  float x0 = p.x - hx, y0 = p.y - hy, x1 = p.x + hx, y1 = p.y + hy;
  float ba = (x1 - x0) * (y1 - y0);
  return iou_corner(tx0, ty0, tx1, ty1, ta, x0, y0, x1, y1, ba);
}

// ---- K1: per (b,a) decode once; per-(b,m) max IoU via staggered LDS atomicMax ----
__global__ void __launch_bounds__(256) t2_kernel(const float4* __restrict__ br,
                                                 const float4* __restrict__ anc,
                                                 const float4* __restrict__ tgt,
                                                 unsigned* __restrict__ maxbits) {
  __shared__ unsigned s_max[NM];
  __shared__ float4 s_t[NM];
  __shared__ float s_ta[NM];
  int b = blockIdx.y;
  int tid = threadIdx.x;
  if (tid < NM) {
    float4 t = tgt[b * NM + tid];
    s_t[tid] = t;
    s_ta[tid] = (t.z - t.x) * (t.w - t.y);
    s_max[tid] = 0u;
  }
  __syncthreads();

  int a = blockIdx.x * 256 + tid;
  float4 p = anc[a];
  float4 l = br[(size_t)b * NA + a];
  float cx = p.x + l.x * VAR0 * p.z;
  float cy = p.y + l.y * VAR0 * p.w;
  float w = p.z * __expf(l.z * VAR1);
  float h = p.w * __expf(l.w * VAR1);
  float dx0 = cx - 0.5f * w, dy0 = cy - 0.5f * h;
  float dx1 = cx + 0.5f * w, dy1 = cy + 0.5f * h;
  float da = (dx1 - dx0) * (dy1 - dy0);

#pragma unroll
  for (int mm = 0; mm < NM; ++mm) {
    int m = (tid + mm) & (NM - 1);           // stagger: spreads atomics over bins
    float4 t = s_t[m];
    float iou = iou_corner(t.x, t.y, t.z, t.w, s_ta[m], dx0, dy0, dx1, dy1, da);
    atomicMax(&s_max[m], __float_as_uint(iou));  // iou >= 0: uint order == float order
  }
  __syncthreads();
  if (tid < NM) atomicMax(&maxbits[b * NM + tid], s_max[tid]);
}

// ---- K2: per (b,m) histogram-select exact top-50 + positive bag loss ----
__global__ void __launch_bounds__(512) pos_kernel(const float4* __restrict__ br,
                                                  const float* __restrict__ cls,
                                                  const float4* __restrict__ anc,
                                                  const float4* __restrict__ tgt,
                                                  const int* __restrict__ labels,
                                                  double* __restrict__ acc) {
  __shared__ int hist[512];
  __shared__ unsigned long long cand[CAP];
  __shared__ int sel[NK];
  __shared__ int s_cnt, s_B1, s_filled;
  __shared__ unsigned char s_flag[512];

  int bm = blockIdx.x;
  int b = bm >> 5;
  int tid = threadIdx.x;
  float4 t = tgt[bm];
  float ta = (t.z - t.x) * (t.w - t.y);

  hist[tid] = 0;
  if (tid == 0) { s_cnt = 0; }
  __syncthreads();

  // Pass 1: histogram of IoU float bits (bits 31..21), zeros excluded.
  for (int a = tid; a < NA; a += 512) {
    float iou = anchor_iou(anc[a], t.x, t.y, t.z, t.w, ta);
    if (iou > 0.f) {
      int bin = (int)(__float_as_uint(iou) >> 21);
      atomicAdd(&hist[bin], 1);
    }
  }
  __syncthreads();

  if (tid == 0) {
    int cum = 0, b1 = 0;
    for (int bin = 511; bin >= 0; --bin) {
      cum += hist[bin];
      if (cum >= NK) { b1 = bin; break; }
    }
    s_B1 = b1;
    s_filled = cum;
  }
  __syncthreads();
  int B1 = s_B1;
  bool zero_path = (s_filled < NK);

  // Pass 2: collect candidates as u64 keys: (valbits<<32) | ~idx.
  for (int a = tid; a < NA; a += 512) {
    float iou = anchor_iou(anc[a], t.x, t.y, t.z, t.w, ta);
    if (iou > 0.f) {
      unsigned vb = __float_as_uint(iou);
      if ((int)(vb >> 21) >= B1) {
        int slot = atomicAdd(&s_cnt, 1);
        if (slot < CAP)
          cand[slot] = ((unsigned long long)vb << 32) | (unsigned)(~a);
      }
    }
  }
  __syncthreads();
  int n = min(s_cnt, CAP);

  // Rank pass (keys unique): rank<NK -> selected.
  for (int c = tid; c < n; c += 512) {
    unsigned long long key = cand[c];
    int rank = 0;
    for (int j = 0; j < n; ++j) rank += (cand[j] > key);
    if (rank < NK) sel[rank] = (int)(~(unsigned)(key & 0xFFFFFFFFull));
  }
  __syncthreads();

  // Degenerate fill: fewer than NK positives -> smallest-index zero-IoU anchors.
  if (zero_path) {
    if (tid == 0) s_filled = n;
    __syncthreads();
    for (int base = 0; base < NA; base += 512) {
      int a = base + tid;
      float iou = anchor_iou(anc[a], t.x, t.y, t.z, t.w, ta);
      s_flag[tid] = (iou == 0.f);
      __syncthreads();
      if (tid == 0) {
        for (int i = 0; i < 512 && s_filled < NK; ++i)
          if (s_flag[i]) { sel[s_filled++] = base + i; }
      }
      __syncthreads();
      if (s_filled >= NK) break;
    }
  }

  // Bag loss on wave 0 (lanes 0..49 active).
  if (tid < 64) {
    int lane = tid;
    float lg = 0.f, wr = 0.f;
    if (lane < NK) {
      int a = sel[lane];
      int lb = labels[bm];
      float4 p = anc[a];
      float4 l = br[(size_t)b * NA + a];
      float logit = cls[((size_t)b * NA + a) * NC + lb];
      float mc = 1.f / (1.f + __expf(-logit));
      float gx = ((t.x + t.z) * 0.5f - p.x) / (VAR0 * p.z);
      float gy = ((t.y + t.w) * 0.5f - p.y) / (VAR0 * p.w);
      float gw = __logf((t.z - t.x) / p.z) / VAR1;
      float gh = __logf((t.w - t.y) / p.w) / VAR1;
      float v0 = gx - l.x, v1 = gy - l.y, v2 = gw - l.z, v3 = gh - l.w;
      float rl = 0.f;
      {
        float av;
        av = fabsf(v0); rl += (av < SL1B) ? (0.5f / SL1B) * v0 * v0 : (av - 0.5f * SL1B);
        av = fabsf(v1); rl += (av < SL1B) ? (0.5f / SL1B) * v1 * v1 : (av - 0.5f * SL1B);
        av = fabsf(v2); rl += (av < SL1B) ? (0.5f / SL1B) * v2 * v2 : (av - 0.5f * SL1B);
        av = fabsf(v3); rl += (av < SL1B) ? (0.5f / SL1B) * v3 * v3 : (av - 0.5f * SL1B);
      }
      rl *= SL1W;
      lg = mc * __expf(-rl);
      wr = 1.f / fmaxf(1.f - lg, FEPS);
    }
    float swl = wr * lg, swr = wr;
    for (int off = 32; off; off >>= 1) { swl += __shfl_down(swl, off); swr += __shfl_down(swr, off); }
    if (lane == 0) {
      float bag = swl / swr;
      float pos = -fmaxf(logf(fmaxf(bag, 1e-38f)), -100.f);
      atomicAdd(acc + 1, (double)pos);
    }
  }
}

// ---- K3: negative (focal) loss over all (b,a,c) ----
__global__ void __launch_bounds__(256) neg_kernel(const float4* __restrict__ br,
                                                  const float* __restrict__ cls,
                                                  const float4* __restrict__ anc,
                                                  const float4* __restrict__ tgt,
                                                  const int* __restrict__ labels,
                                                  const unsigned* __restrict__ maxbits,
                                                  double* __restrict__ acc) {
  __shared__ float s_obp[NM][256];
  __shared__ float4 s_t[NM];
  __shared__ float s_ta[NM], s_inv[NM];
  __shared__ unsigned s_cmask[NC];
  int b = blockIdx.y;
  int tid = threadIdx.x;
  if (tid < NC) s_cmask[tid] = 0u;
  __syncthreads();
  if (tid < NM) {
    float4 t = tgt[b * NM + tid];
    s_t[tid] = t;
    s_ta[tid] = (t.z - t.x) * (t.w - t.y);
    float mx = __uint_as_float(maxbits[b * NM + tid]);
    s_inv[tid] = 1.0f / (fmaxf(mx, T1f) - T1f);   // T1+1e-12 rounds to 0.5f in fp32
    atomicOr(&s_cmask[labels[b * NM + tid]], 1u << tid);
  }
  __syncthreads();

  int a = blockIdx.x * 256 + tid;
  float4 p = anc[a];
  float4 l = br[(size_t)b * NA + a];
  float cx = p.x + l.x * VAR0 * p.z;
  float cy = p.y + l.y * VAR0 * p.w;
  float w = p.z * __expf(l.z * VAR1);
  float h = p.w * __expf(l.w * VAR1);
  float dx0 = cx - 0.5f * w, dy0 = cy - 0.5f * h;
  float dx1 = cx + 0.5f * w, dy1 = cy + 0.5f * h;
  float da = (dx1 - dx0) * (dy1 - dy0);

#pragma unroll
  for (int m = 0; m < NM; ++m) {
    float4 t = s_t[m];
    float iou = iou_corner(t.x, t.y, t.z, t.w, s_ta[m], dx0, dy0, dx1, dy1, da);
    float o = (iou - T1f) * s_inv[m];
    s_obp[m][tid] = fminf(fmaxf(o, 0.f), 1.f);
  }
  __syncthreads();

  const float4* row = (const float4*)(cls + ((size_t)b * NA + a) * NC);
  float accum = 0.f;
#pragma unroll 4
  for (int j = 0; j < NC / 4; ++j) {
    float4 v = row[j];
    float vv0 = v.x, vv1 = v.y, vv2 = v.z, vv3 = v.w;
#pragma unroll
    for (int e = 0; e < 4; ++e) {
      float lv = (e == 0) ? vv0 : (e == 1) ? vv1 : (e == 2) ? vv2 : vv3;
      int c = 4 * j + e;
      unsigned mk = s_cmask[c];
      float bp = 0.f;
      while (mk) {
        int mm = __ffs(mk) - 1;
        mk &= mk - 1;
        bp = fmaxf(bp, s_obp[mm][tid]);
      }
      float s = 1.f / (1.f + __expf(-lv));
      float pr = s * (1.f - bp);
      float om = fmaxf(1.f - pr, 1e-38f);
      accum += pr * pr * fminf(-__logf(om), 100.f);
    }
  }

  for (int off = 32; off; off >>= 1) accum += __shfl_down(accum, off);
  __shared__ float swave[4];
  if ((tid & 63) == 0) swave[tid >> 6] = accum;
  __syncthreads();
  if (tid == 0) atomicAdd(acc, (double)(swave[0] + swave[1] + swave[2] + swave[3]));
}

// ---- K4: finalize ----
__global__ void fin_kernel(const double* __restrict__ acc, float* __restrict__ out) {
  out[0] = (float)(acc[1] / 256.0 * 0.5);
  out[1] = (float)(acc[0] / 12800.0 * 0.5);
}

extern "C" void kernel_launch(void* const* d_in, const int* in_sizes, int n_in,
                              void* d_out, int out_size, void* d_ws, size_t ws_size,
                              hipStream_t stream) {
  const float4* br  = (const float4*)d_in[0];
  const float*  cls = (const float*)d_in[1];
  const float4* anc = (const float4*)d_in[2];
  const float4* tgt = (const float4*)d_in[3];
  const int*    lab = (const int*)d_in[4];
  float* out = (float*)d_out;
  double* acc = (double*)d_ws;                        // [0]=neg, [1]=pos
  unsigned* maxbits = (unsigned*)((char*)d_ws + 16);  // 256 u32 (0x0 == 0.0f)

  hipMemsetAsync(d_ws, 0, 16 + NB * NM * sizeof(unsigned), stream);
  t2_kernel<<<dim3(NA / 256, NB), 256, 0, stream>>>(br, anc, tgt, maxbits);
  pos_kernel<<<dim3(NB * NM), 512, 0, stream>>>(br, cls, anc, tgt, lab, acc);
  neg_kernel<<<dim3(NA / 256, NB), 256, 0, stream>>>(br, cls, anc, tgt, lab, maxbits, acc);
  fin_kernel<<<1, 1, 0, stream>>>(acc, out);
}